// Round 2
// baseline (9221.965 us; speedup 1.0000x reference)
//
#include <hip/hip_runtime.h>
#include <math.h>

#define B_SZ 4096
#define T_SZ 80
#define V_SZ 80
#define E_SZ 8
#define H_SZ 256
#define G4   1024   // 4*H

__device__ __forceinline__ float sigm(float x) {
    return 1.f / (1.f + __expf(-x));
}
__device__ __forceinline__ float tanhfast(float x) {
    x = fminf(fmaxf(x, -15.f), 15.f);
    float t = __expf(-2.f * x);
    return (1.f - t) / (1.f + t);
}

// G1[v][col] = b1[col] + sum_e emb[v][e] * W1[e][col]   (layer-1 input+bias table)
__global__ __launch_bounds__(256) void g1_kernel(const float* __restrict__ emb,
                                                 const float* __restrict__ W1,
                                                 const float* __restrict__ b1,
                                                 float* __restrict__ G1) {
    int idx = blockIdx.x * 256 + threadIdx.x;
    if (idx >= V_SZ * G4) return;
    int v = idx >> 10, col = idx & 1023;
    float g = b1[col];
#pragma unroll
    for (int e = 0; e < E_SZ; e++)
        g += emb[v * E_SZ + e] * W1[e * G4 + col];
    G1[idx] = g;
}

// One LSTM timestep (both layers use this kernel).
//  layer1: Ax=null; A = h1_prev [B,256]; W = W1h (rows 0..255); init = G1[feat[b]]
//  layer2: Ax=h1_t  [B,256] (K rows 0..255); Ah=h2_prev (K rows 256..511); W = W2; init = b2
// Block: BM=64 batch rows x BH=32 h-cols, computing all 4 gates; fused cell update.
__global__ __launch_bounds__(256) void lstm_step(
    const float* __restrict__ Ax, int ldax,
    const float* __restrict__ Ah, int ldah,
    const float* __restrict__ W,      // [K,1024] row-major
    const float* __restrict__ G1,     // layer1 only
    const int*   __restrict__ feat,   // layer1 only: features + t (stride T per row)
    const float* __restrict__ bias,   // layer2 only
    float* __restrict__ cbuf,         // [B,H]
    int t0,
    float* __restrict__ hout, int ldho) {

    __shared__ float As[32][68];   // [k][m], padded
    __shared__ float Ws[32][132];  // [k][4*32 cols], padded

    const int tid = threadIdx.x;
    const int m0 = blockIdx.x * 64;
    const int h0 = blockIdx.y * 32;
    const int tm = tid >> 4;          // 0..15 -> rows tm*4..tm*4+3
    const int tc = (tid & 15) * 2;    // 0..30 -> 2 h-cols

    const bool isL2 = (Ax != nullptr);
    const int Kend = isL2 ? (t0 ? 256 : 512) : (t0 ? 0 : 256);

    float acc[4][4][2];
#pragma unroll
    for (int g = 0; g < 4; g++)
#pragma unroll
        for (int m = 0; m < 4; m++) { acc[g][m][0] = 0.f; acc[g][m][1] = 0.f; }

    for (int kt = 0; kt < Kend; kt += 32) {
        const float* Asrc;
        int lda, kcb;
        if (isL2 && kt >= 256) { Asrc = Ah; lda = ldah; kcb = kt - 256; }
        else if (isL2)         { Asrc = Ax; lda = ldax; kcb = kt; }
        else                   { Asrc = Ah; lda = ldah; kcb = kt; }

        __syncthreads();
        // A tile 64 rows x 32 k, transposed into As[k][m]
#pragma unroll
        for (int i = 0; i < 2; i++) {
            int idx = tid + i * 256;
            int row = idx >> 3, kq = idx & 7;
            const float4 v = *(const float4*)&Asrc[(size_t)(m0 + row) * lda + kcb + kq * 4];
            As[kq * 4 + 0][row] = v.x;
            As[kq * 4 + 1][row] = v.y;
            As[kq * 4 + 2][row] = v.z;
            As[kq * 4 + 3][row] = v.w;
        }
        // W tile: 32 k-rows x (4 gates x 32 h-cols)
#pragma unroll
        for (int i = 0; i < 4; i++) {
            int idx = tid + i * 256;
            int kr = idx >> 5, c4 = idx & 31;
            int g = c4 >> 3, hh = (c4 & 7) * 4;
            const float4 v = *(const float4*)&W[(size_t)(kt + kr) * G4 + g * 256 + h0 + hh];
            *(float4*)&Ws[kr][c4 * 4] = v;
        }
        __syncthreads();

#pragma unroll
        for (int kk = 0; kk < 32; kk++) {
            float4 a = *(const float4*)&As[kk][tm * 4];
            float2 bb0 = *(const float2*)&Ws[kk][0 + tc];
            float2 bb1 = *(const float2*)&Ws[kk][32 + tc];
            float2 bb2 = *(const float2*)&Ws[kk][64 + tc];
            float2 bb3 = *(const float2*)&Ws[kk][96 + tc];
            const float am[4] = {a.x, a.y, a.z, a.w};
#pragma unroll
            for (int m = 0; m < 4; m++) {
                acc[0][m][0] = fmaf(am[m], bb0.x, acc[0][m][0]);
                acc[0][m][1] = fmaf(am[m], bb0.y, acc[0][m][1]);
                acc[1][m][0] = fmaf(am[m], bb1.x, acc[1][m][0]);
                acc[1][m][1] = fmaf(am[m], bb1.y, acc[1][m][1]);
                acc[2][m][0] = fmaf(am[m], bb2.x, acc[2][m][0]);
                acc[2][m][1] = fmaf(am[m], bb2.y, acc[2][m][1]);
                acc[3][m][0] = fmaf(am[m], bb3.x, acc[3][m][0]);
                acc[3][m][1] = fmaf(am[m], bb3.y, acc[3][m][1]);
            }
        }
    }

    // fused LSTM cell epilogue
#pragma unroll
    for (int m = 0; m < 4; m++) {
        const int bg = m0 + tm * 4 + m;
        int featv = 0;
        if (!isL2) featv = feat[(size_t)bg * T_SZ];
#pragma unroll
        for (int hh = 0; hh < 2; hh++) {
            const int hg = h0 + tc + hh;
            float gi, gj, gf, go;
            if (isL2) {
                gi = acc[0][m][hh] + bias[hg];
                gj = acc[1][m][hh] + bias[256 + hg];
                gf = acc[2][m][hh] + bias[512 + hg];
                go = acc[3][m][hh] + bias[768 + hg];
            } else {
                const float* gr = G1 + (size_t)featv * G4;
                gi = acc[0][m][hh] + gr[hg];
                gj = acc[1][m][hh] + gr[256 + hg];
                gf = acc[2][m][hh] + gr[512 + hg];
                go = acc[3][m][hh] + gr[768 + hg];
            }
            float cp = t0 ? 0.f : cbuf[(size_t)bg * H_SZ + hg];
            float cn = cp * sigm(gf + 1.f) + sigm(gi) * tanhfast(gj);
            float hn = tanhfast(cn) * sigm(go);
            cbuf[(size_t)bg * H_SZ + hg] = cn;
            hout[(size_t)bg * ldho + hg] = hn;
        }
    }
}

// pred = h2_last @ Wd + bd; loss_b = logsumexp(pred) - pred[label]; mean via atomicAdd
__global__ __launch_bounds__(128) void dense_loss(const float* __restrict__ h2,
                                                  const float* __restrict__ Wd,
                                                  const float* __restrict__ bd,
                                                  const int* __restrict__ labels,
                                                  float* __restrict__ out) {
    __shared__ float hrow[H_SZ];
    __shared__ float pv[V_SZ];
    const int b = blockIdx.x, tid = threadIdx.x;
    hrow[tid] = h2[(size_t)b * H_SZ + tid];
    hrow[tid + 128] = h2[(size_t)b * H_SZ + tid + 128];
    __syncthreads();
    if (tid < V_SZ) {
        float s = bd[tid];
#pragma unroll 8
        for (int h = 0; h < H_SZ; h++)
            s = fmaf(hrow[h], Wd[h * V_SZ + tid], s);
        pv[tid] = s;
    }
    __syncthreads();
    if (tid < 64) {
        float a = pv[tid];
        float b2v = (tid < V_SZ - 64) ? pv[tid + 64] : -1e30f;
        float mx = fmaxf(a, b2v);
#pragma unroll
        for (int off = 32; off; off >>= 1)
            mx = fmaxf(mx, __shfl_xor(mx, off, 64));
        float s = __expf(a - mx) + ((tid < V_SZ - 64) ? __expf(pv[tid + 64] - mx) : 0.f);
#pragma unroll
        for (int off = 32; off; off >>= 1)
            s += __shfl_xor(s, off, 64);
        if (tid == 0) {
            float loss = logf(s) + mx - pv[labels[b]];
            atomicAdd(out, loss * (1.0f / B_SZ));
        }
    }
}

extern "C" void kernel_launch(void* const* d_in, const int* in_sizes, int n_in,
                              void* d_out, int out_size, void* d_ws, size_t ws_size,
                              hipStream_t stream) {
    const int*   features = (const int*)d_in[0];
    const int*   labels   = (const int*)d_in[1];
    const float* emb      = (const float*)d_in[2];
    const float* W1       = (const float*)d_in[3];
    const float* b1       = (const float*)d_in[4];
    const float* W2       = (const float*)d_in[5];
    const float* b2       = (const float*)d_in[6];
    const float* Wd       = (const float*)d_in[7];
    const float* bd       = (const float*)d_in[8];
    float* out = (float*)d_out;
    float* ws  = (float*)d_ws;

    const size_t BH = (size_t)B_SZ * H_SZ;  // 1M floats
    float* G1v = ws;
    float* c1  = ws + (size_t)V_SZ * G4;
    float* c2  = c1 + BH;
    float* h1buf[2] = {c2 + BH, c2 + 2 * BH};
    float* h2buf[2] = {c2 + 3 * BH, c2 + 4 * BH};

    (void)hipMemsetAsync(d_out, 0, sizeof(float), stream);
    g1_kernel<<<(V_SZ * G4 + 255) / 256, 256, 0, stream>>>(emb, W1, b1, G1v);

    dim3 grid(B_SZ / 64, H_SZ / 32), blk(256);
    for (int t = 0; t < T_SZ; t++) {
        const int t0 = (t == 0);
        const float* h1prev = t0 ? nullptr : h1buf[(t - 1) & 1];
        lstm_step<<<grid, blk, 0, stream>>>(nullptr, 0, h1prev, H_SZ,
                                            W1 + E_SZ * G4, G1v, features + t,
                                            nullptr, c1, t0, h1buf[t & 1], H_SZ);
        const float* h2prev = t0 ? nullptr : h2buf[(t - 1) & 1];
        lstm_step<<<grid, blk, 0, stream>>>(h1buf[t & 1], H_SZ, h2prev, H_SZ,
                                            W2, nullptr, nullptr,
                                            b2, c2, t0, h2buf[t & 1], H_SZ);
    }
    dense_loss<<<B_SZ, 128, 0, stream>>>(h2buf[(T_SZ - 1) & 1], Wd, bd, labels, out);
}

// Round 3
// 4406.539 us; speedup vs baseline: 2.0928x; 2.0928x over previous
//
#include <hip/hip_runtime.h>
#include <math.h>

#define B_SZ 4096
#define T_SZ 80
#define V_SZ 80
#define E_SZ 8
#define H_SZ 256
#define G4   1024   // 4*H

typedef __attribute__((ext_vector_type(8))) short short8;
typedef __attribute__((ext_vector_type(4))) float f32x4;

__device__ __forceinline__ float sigm(float x) {
    return 1.f / (1.f + __expf(-x));
}
__device__ __forceinline__ float tanhfast(float x) {
    x = fminf(fmaxf(x, -15.f), 15.f);
    float t = __expf(-2.f * x);
    return (1.f - t) / (1.f + t);
}
__device__ __forceinline__ ushort f2bf(float f) {   // RNE f32->bf16
    unsigned u = __float_as_uint(f);
    u = (u + 0x7fffu + ((u >> 16) & 1u)) >> 16;
    return (ushort)u;
}
__device__ __forceinline__ float bf2f(ushort s) {
    return __uint_as_float(((unsigned)s) << 16);
}

// G1[v][col] = b1[col] + sum_e emb[v][e] * W1[e][col]
__global__ __launch_bounds__(256) void g1_kernel(const float* __restrict__ emb,
                                                 const float* __restrict__ W1,
                                                 const float* __restrict__ b1,
                                                 float* __restrict__ G1) {
    int idx = blockIdx.x * 256 + threadIdx.x;
    if (idx >= V_SZ * G4) return;
    int v = idx >> 10, col = idx & 1023;
    float g = b1[col];
#pragma unroll
    for (int e = 0; e < E_SZ; e++)
        g += emb[v * E_SZ + e] * W1[e * G4 + col];
    G1[idx] = g;
}

// Wt[n][k] = bf16(src[(k0+k)*1024 + n]),  n in [0,1024), k in [0,K)
__global__ __launch_bounds__(256) void wtrans(const float* __restrict__ src, int k0,
                                              int Kshift, ushort* __restrict__ out) {
    const int K = 1 << Kshift;
    int idx = blockIdx.x * 256 + threadIdx.x;
    int n = idx >> Kshift, k = idx & (K - 1);
    out[idx] = f2bf(src[(size_t)(k0 + k) * G4 + n]);
}

// Fused step kernel: blockIdx.z==0 -> layer1(t); z==1 -> layer2(t-1).
// Block computes 64 rows x (4 gates x 32 hcols). 4 waves; wave w owns rows
// w*16..w*16+15, all 128 cols -> all 4 gates per (row,h) in one thread.
// No LDS: A and B fragments are direct 16B global loads (L2-resident).
__global__ __launch_bounds__(256) void lstm_fused(
    const ushort* __restrict__ A1h, int Kend1,
    const int*   __restrict__ feat,   // features + t
    const float* __restrict__ G1,
    float* __restrict__ c1, ushort* __restrict__ h1out,
    const ushort* __restrict__ A2x, const ushort* __restrict__ A2h, int Kend2,
    const float* __restrict__ b2,
    float* __restrict__ c2, ushort* __restrict__ h2out,
    const ushort* __restrict__ W1t, const ushort* __restrict__ W2t) {

    const int z = blockIdx.z;
    const int Kend = z ? Kend2 : Kend1;
    if (Kend < 0) return;
    const int K = z ? 512 : 256;
    const ushort* __restrict__ Wt = z ? W2t : W1t;

    const int tid = threadIdx.x;
    const int w = tid >> 6, l = tid & 63;
    const int l15 = l & 15, l4 = l >> 4;
    const int koff = l4 * 8;
    const int m0 = blockIdx.x * 64;
    const int h0 = blockIdx.y * 32;

    f32x4 acc[8];
    const f32x4 zero4 = {0.f, 0.f, 0.f, 0.f};
#pragma unroll
    for (int cf = 0; cf < 8; cf++) acc[cf] = zero4;

    const ushort* wp[8];
#pragma unroll
    for (int cf = 0; cf < 8; cf++) {
        int ncol = (cf >> 1) * 256 + h0 + (cf & 1) * 16 + l15;
        wp[cf] = Wt + (size_t)ncol * K + koff;
    }
    const size_t arow_off = (size_t)(m0 + w * 16 + l15) * H_SZ + koff;

    for (int kt = 0; kt < Kend; kt += 32) {
        const ushort* Asrc;
        int kl;
        if (!z)            { Asrc = A1h; kl = kt; }
        else if (kt < 256) { Asrc = A2x; kl = kt; }
        else               { Asrc = A2h; kl = kt - 256; }
        short8 a = *reinterpret_cast<const short8*>(Asrc + arow_off + kl);

        short8 bq[8];
#pragma unroll
        for (int cf = 0; cf < 8; cf++)
            bq[cf] = *reinterpret_cast<const short8*>(wp[cf] + kt);
#pragma unroll
        for (int cf = 0; cf < 8; cf++)
            acc[cf] = __builtin_amdgcn_mfma_f32_16x16x32_bf16(a, bq[cf], acc[cf], 0, 0, 0);
    }

    // fused LSTM cell epilogue. D layout: row=(l>>4)*4+r, col=l&15 (verified).
    float* __restrict__ cbuf = z ? c2 : c1;
    ushort* __restrict__ hout = z ? h2out : h1out;
    const bool cz = z ? (Kend == 256) : (Kend == 0);   // first timestep for this layer

#pragma unroll
    for (int r = 0; r < 4; r++) {
        const int grow = m0 + w * 16 + l4 * 4 + r;
        const float* gr = nullptr;
        if (!z) gr = G1 + (size_t)feat[(size_t)grow * T_SZ] * G4;
#pragma unroll
        for (int h16 = 0; h16 < 2; h16++) {
            const int hcol = h0 + h16 * 16 + l15;
            float gi = acc[0 + h16][r];
            float gj = acc[2 + h16][r];
            float gf = acc[4 + h16][r];
            float go = acc[6 + h16][r];
            if (!z) {
                gi += gr[hcol]; gj += gr[256 + hcol];
                gf += gr[512 + hcol]; go += gr[768 + hcol];
            } else {
                gi += b2[hcol]; gj += b2[256 + hcol];
                gf += b2[512 + hcol]; go += b2[768 + hcol];
            }
            const size_t ci = (size_t)grow * H_SZ + hcol;
            float cp = cz ? 0.f : cbuf[ci];
            float cn = cp * sigm(gf + 1.f) + sigm(gi) * tanhfast(gj);
            float hn = tanhfast(cn) * sigm(go);
            cbuf[ci] = cn;
            hout[ci] = f2bf(hn);
        }
    }
}

// pred = h2_last @ Wd + bd; loss = mean(logsumexp(pred) - pred[label])
__global__ __launch_bounds__(128) void dense_loss(const ushort* __restrict__ h2,
                                                  const float* __restrict__ Wd,
                                                  const float* __restrict__ bd,
                                                  const int* __restrict__ labels,
                                                  float* __restrict__ out) {
    __shared__ float hrow[H_SZ];
    __shared__ float pv[V_SZ];
    const int b = blockIdx.x, tid = threadIdx.x;
    hrow[tid] = bf2f(h2[(size_t)b * H_SZ + tid]);
    hrow[tid + 128] = bf2f(h2[(size_t)b * H_SZ + tid + 128]);
    __syncthreads();
    if (tid < V_SZ) {
        float s = bd[tid];
#pragma unroll 8
        for (int h = 0; h < H_SZ; h++)
            s = fmaf(hrow[h], Wd[h * V_SZ + tid], s);
        pv[tid] = s;
    }
    __syncthreads();
    if (tid < 64) {
        float a = pv[tid];
        float b2v = (tid < V_SZ - 64) ? pv[tid + 64] : -1e30f;
        float mx = fmaxf(a, b2v);
#pragma unroll
        for (int off = 32; off; off >>= 1)
            mx = fmaxf(mx, __shfl_xor(mx, off, 64));
        float s = __expf(a - mx) + ((tid < V_SZ - 64) ? __expf(pv[tid + 64] - mx) : 0.f);
#pragma unroll
        for (int off = 32; off; off >>= 1)
            s += __shfl_xor(s, off, 64);
        if (tid == 0) {
            float loss = logf(s) + mx - pv[labels[b]];
            atomicAdd(out, loss * (1.0f / B_SZ));
        }
    }
}

extern "C" void kernel_launch(void* const* d_in, const int* in_sizes, int n_in,
                              void* d_out, int out_size, void* d_ws, size_t ws_size,
                              hipStream_t stream) {
    const int*   features = (const int*)d_in[0];
    const int*   labels   = (const int*)d_in[1];
    const float* emb      = (const float*)d_in[2];
    const float* W1       = (const float*)d_in[3];
    const float* b1       = (const float*)d_in[4];
    const float* W2       = (const float*)d_in[5];
    const float* b2       = (const float*)d_in[6];
    const float* Wd       = (const float*)d_in[7];
    const float* bd       = (const float*)d_in[8];
    float* out = (float*)d_out;

    char* base = (char*)d_ws;
    float*  G1v = (float*)base;                      base += (size_t)V_SZ * G4 * 4;      // 320 KB
    float*  c1  = (float*)base;                      base += (size_t)B_SZ * H_SZ * 4;    // 4 MB
    float*  c2  = (float*)base;                      base += (size_t)B_SZ * H_SZ * 4;    // 4 MB
    ushort* h1b[2]; ushort* h2b[2];
    h1b[0] = (ushort*)base;                          base += (size_t)B_SZ * H_SZ * 2;
    h1b[1] = (ushort*)base;                          base += (size_t)B_SZ * H_SZ * 2;
    h2b[0] = (ushort*)base;                          base += (size_t)B_SZ * H_SZ * 2;
    h2b[1] = (ushort*)base;                          base += (size_t)B_SZ * H_SZ * 2;
    ushort* W1t = (ushort*)base;                     base += (size_t)G4 * H_SZ * 2;      // 512 KB
    ushort* W2t = (ushort*)base;                     base += (size_t)G4 * 2 * H_SZ * 2;  // 1 MB

    (void)hipMemsetAsync(d_out, 0, sizeof(float), stream);
    g1_kernel<<<(V_SZ * G4 + 255) / 256, 256, 0, stream>>>(emb, W1, b1, G1v);
    wtrans<<<(G4 * 256) / 256, 256, 0, stream>>>(W1, E_SZ, 8, W1t);
    wtrans<<<(G4 * 512) / 256, 256, 0, stream>>>(W2, 0, 9, W2t);

    dim3 grid(B_SZ / 64, H_SZ / 32, 2), blk(256);
    for (int t = 0; t <= T_SZ; t++) {
        const int Kend1 = (t < T_SZ) ? (t ? 256 : 0) : -1;
        const int Kend2 = (t >= 1) ? ((t >= 2) ? 512 : 256) : -1;
        lstm_fused<<<grid, blk, 0, stream>>>(
            (t && t < T_SZ) ? h1b[(t - 1) & 1] : nullptr, Kend1,
            features + t, G1v, c1, h1b[t & 1],
            (t >= 1) ? h1b[(t - 1) & 1] : nullptr,
            (t >= 2) ? h2b[(t - 2) & 1] : nullptr, Kend2,
            b2, c2, (t >= 1) ? h2b[(t - 1) & 1] : nullptr,
            W1t, W2t);
    }
    dense_loss<<<B_SZ, 128, 0, stream>>>(h2b[(T_SZ - 1) & 1], Wd, bd, labels, out);
}

// Round 4
// 1906.023 us; speedup vs baseline: 4.8383x; 2.3119x over previous
//
#include <hip/hip_runtime.h>
#include <math.h>

#define B_SZ 4096
#define T_SZ 80
#define V_SZ 80
#define E_SZ 8
#define H_SZ 256
#define G4   1024   // 4*H

typedef __attribute__((ext_vector_type(8))) short short8;
typedef __attribute__((ext_vector_type(4))) float f32x4;

__device__ __forceinline__ float sigm(float x) {
    return 1.f / (1.f + __expf(-x));
}
__device__ __forceinline__ float tanhfast(float x) {
    x = fminf(fmaxf(x, -15.f), 15.f);
    float t = __expf(-2.f * x);
    return (1.f - t) / (1.f + t);
}
__device__ __forceinline__ ushort f2bf(float f) {   // RNE f32->bf16
    unsigned u = __float_as_uint(f);
    u = (u + 0x7fffu + ((u >> 16) & 1u)) >> 16;
    return (ushort)u;
}

// G1[v][col] = b1[col] + sum_e emb[v][e] * W1[e][col]
__global__ __launch_bounds__(256) void g1_kernel(const float* __restrict__ emb,
                                                 const float* __restrict__ W1,
                                                 const float* __restrict__ b1,
                                                 float* __restrict__ G1) {
    int idx = blockIdx.x * 256 + threadIdx.x;
    if (idx >= V_SZ * G4) return;
    int v = idx >> 10, col = idx & 1023;
    float g = b1[col];
#pragma unroll
    for (int e = 0; e < E_SZ; e++)
        g += emb[v * E_SZ + e] * W1[e * G4 + col];
    G1[idx] = g;
}

// Wt[n][k] = bf16(src[(k0+k)*1024 + n])
__global__ __launch_bounds__(256) void wtrans(const float* __restrict__ src, int k0,
                                              int Kshift, ushort* __restrict__ out) {
    const int K = 1 << Kshift;
    int idx = blockIdx.x * 256 + threadIdx.x;
    int n = idx >> Kshift, k = idx & (K - 1);
    out[idx] = f2bf(src[(size_t)(k0 + k) * G4 + n]);
}

// WdT[v][h] = bf16(Wd[h*V + v])
__global__ __launch_bounds__(256) void wdtrans(const float* __restrict__ src,
                                               ushort* __restrict__ out) {
    int idx = blockIdx.x * 256 + threadIdx.x;
    if (idx >= V_SZ * H_SZ) return;
    int v = idx >> 8, h = idx & 255;
    out[idx] = f2bf(src[h * V_SZ + v]);
}

// Fused step: blockIdx.z==0 -> layer1(t); z==1 -> layer2(t-1).
// Block = 128 rows x (4 gates x 32 hcols); 4 waves, wave w owns rows w*32..w*32+31.
// A and W tiles LDS-staged (rows padded to 40 shorts -> conflict-light).
__global__ __launch_bounds__(256) void lstm_fused(
    const ushort* __restrict__ A1h, int Kend1,
    const int*   __restrict__ feat,   // features + t
    const float* __restrict__ G1,
    float* __restrict__ c1, ushort* __restrict__ h1out,
    const ushort* __restrict__ A2x, const ushort* __restrict__ A2h, int Kend2,
    const float* __restrict__ b2,
    float* __restrict__ c2, ushort* __restrict__ h2out,
    const ushort* __restrict__ W1t, const ushort* __restrict__ W2t) {

    const int z = blockIdx.z;
    const int Kend = z ? Kend2 : Kend1;
    if (Kend < 0) return;
    const int K = z ? 512 : 256;
    const ushort* __restrict__ Wt = z ? W2t : W1t;

    __shared__ ushort As[128 * 40];
    __shared__ ushort Ws[128 * 40];

    const int tid = threadIdx.x;
    const int w = tid >> 6, l = tid & 63;
    const int l15 = l & 15, l4 = l >> 4;
    const int m0 = blockIdx.x * 128;
    const int h0 = blockIdx.y * 32;

    // staging geometry: 512 16B-chunks per tile, thread does chunks tid and tid+256
    const int row0 = tid >> 2, c40 = tid & 3;       // rows 0..63
    const int row1 = row0 + 64;                     // rows 64..127
    const int ncol0 = ((row0) >> 5) * 256 + h0 + (row0 & 31);   // col == chunk>>2 for W
    const int ncol1 = ((row1) >> 5) * 256 + h0 + (row1 & 31);
    const size_t wbase0 = (size_t)ncol0 * K + c40 * 8;
    const size_t wbase1 = (size_t)ncol1 * K + c40 * 8;
    const int lA0 = row0 * 40 + c40 * 8, lA1 = row1 * 40 + c40 * 8;

    // fragment read offsets (ushort indices)
    const int aoff0 = (w * 32 + l15) * 40 + l4 * 8;
    const int aoff1 = aoff0 + 16 * 40;
    const int boff  = l15 * 40 + l4 * 8;

    f32x4 acc[2][8];
    const f32x4 zero4 = {0.f, 0.f, 0.f, 0.f};
#pragma unroll
    for (int fg = 0; fg < 2; fg++)
#pragma unroll
        for (int cf = 0; cf < 8; cf++) acc[fg][cf] = zero4;

    for (int kt = 0; kt < Kend; kt += 32) {
        const ushort* Asrc;
        int kl;
        if (!z)            { Asrc = A1h; kl = kt; }
        else if (kt < 256) { Asrc = A2x; kl = kt; }
        else               { Asrc = A2h; kl = kt - 256; }

        // issue global loads first (overlap with previous iteration's MFMAs)
        short8 ga0 = *(const short8*)(Asrc + (size_t)(m0 + row0) * H_SZ + kl + c40 * 8);
        short8 ga1 = *(const short8*)(Asrc + (size_t)(m0 + row1) * H_SZ + kl + c40 * 8);
        short8 gw0 = *(const short8*)(Wt + wbase0 + kt);
        short8 gw1 = *(const short8*)(Wt + wbase1 + kt);

        __syncthreads();
        *(short8*)(As + lA0) = ga0;
        *(short8*)(As + lA1) = ga1;
        *(short8*)(Ws + lA0) = gw0;
        *(short8*)(Ws + lA1) = gw1;
        __syncthreads();

        short8 a0 = *(const short8*)(As + aoff0);
        short8 a1 = *(const short8*)(As + aoff1);
#pragma unroll
        for (int cf = 0; cf < 8; cf++) {
            short8 b = *(const short8*)(Ws + boff + cf * 640);
            acc[0][cf] = __builtin_amdgcn_mfma_f32_16x16x32_bf16(a0, b, acc[0][cf], 0, 0, 0);
            acc[1][cf] = __builtin_amdgcn_mfma_f32_16x16x32_bf16(a1, b, acc[1][cf], 0, 0, 0);
        }
    }

    // fused LSTM cell epilogue. D layout: row=(l>>4)*4+r, col=l&15.
    float* __restrict__ cbuf = z ? c2 : c1;
    ushort* __restrict__ hout = z ? h2out : h1out;
    const bool cz = z ? (Kend == 256) : (Kend == 0);

#pragma unroll
    for (int fg = 0; fg < 2; fg++) {
#pragma unroll
        for (int r = 0; r < 4; r++) {
            const int grow = m0 + w * 32 + fg * 16 + l4 * 4 + r;
            const float* gb = z ? b2 : (G1 + (size_t)feat[(size_t)grow * T_SZ] * G4);
#pragma unroll
            for (int h16 = 0; h16 < 2; h16++) {
                const int hcol = h0 + h16 * 16 + l15;
                float gi = acc[fg][0 + h16][r] + gb[hcol];
                float gj = acc[fg][2 + h16][r] + gb[256 + hcol];
                float gf = acc[fg][4 + h16][r] + gb[512 + hcol];
                float go = acc[fg][6 + h16][r] + gb[768 + hcol];
                const size_t ci = (size_t)grow * H_SZ + hcol;
                float cp = cz ? 0.f : cbuf[ci];
                float cn = cp * sigm(gf + 1.f) + sigm(gi) * tanhfast(gj);
                float hn = tanhfast(cn) * sigm(go);
                cbuf[ci] = cn;
                hout[ci] = f2bf(hn);
            }
        }
    }
}

// dense+loss via MFMA: wave computes 16 rows x 80 v-cols; shfl softmax.
__global__ __launch_bounds__(256) void dense_loss(const ushort* __restrict__ h2,
                                                  const ushort* __restrict__ WdT,
                                                  const float* __restrict__ bd,
                                                  const int* __restrict__ labels,
                                                  float* __restrict__ out) {
    const int tid = threadIdx.x;
    const int w = tid >> 6, l = tid & 63;
    const int l15 = l & 15, l4 = l >> 4;
    const int m0 = blockIdx.x * 64 + w * 16;

    f32x4 acc[5];
    const f32x4 zero4 = {0.f, 0.f, 0.f, 0.f};
#pragma unroll
    for (int cf = 0; cf < 5; cf++) acc[cf] = zero4;

    for (int kt = 0; kt < 256; kt += 32) {
        short8 a = *(const short8*)(h2 + (size_t)(m0 + l15) * H_SZ + l4 * 8 + kt);
#pragma unroll
        for (int cf = 0; cf < 5; cf++) {
            short8 b = *(const short8*)(WdT + (size_t)(cf * 16 + l15) * H_SZ + l4 * 8 + kt);
            acc[cf] = __builtin_amdgcn_mfma_f32_16x16x32_bf16(a, b, acc[cf], 0, 0, 0);
        }
    }
    const float bdv = bd[0 * 16 + l15];  // per-cf below
    (void)bdv;
#pragma unroll
    for (int cf = 0; cf < 5; cf++) {
        float bv = bd[cf * 16 + l15];
#pragma unroll
        for (int r = 0; r < 4; r++) acc[cf][r] += bv;
    }

#pragma unroll
    for (int r = 0; r < 4; r++) {
        const int row = m0 + l4 * 4 + r;
        float mx = acc[0][r];
#pragma unroll
        for (int cf = 1; cf < 5; cf++) mx = fmaxf(mx, acc[cf][r]);
#pragma unroll
        for (int msk = 1; msk < 16; msk <<= 1)
            mx = fmaxf(mx, __shfl_xor(mx, msk, 64));
        float s = 0.f;
#pragma unroll
        for (int cf = 0; cf < 5; cf++) s += __expf(acc[cf][r] - mx);
#pragma unroll
        for (int msk = 1; msk < 16; msk <<= 1)
            s += __shfl_xor(s, msk, 64);
        const int lab = labels[row];
        float pl = 0.f;
#pragma unroll
        for (int cf = 0; cf < 5; cf++)
            pl += (cf * 16 + l15 == lab) ? acc[cf][r] : 0.f;
#pragma unroll
        for (int msk = 1; msk < 16; msk <<= 1)
            pl += __shfl_xor(pl, msk, 64);
        if (l15 == 0)
            atomicAdd(out, (logf(s) + mx - pl) * (1.0f / B_SZ));
    }
}

extern "C" void kernel_launch(void* const* d_in, const int* in_sizes, int n_in,
                              void* d_out, int out_size, void* d_ws, size_t ws_size,
                              hipStream_t stream) {
    const int*   features = (const int*)d_in[0];
    const int*   labels   = (const int*)d_in[1];
    const float* emb      = (const float*)d_in[2];
    const float* W1       = (const float*)d_in[3];
    const float* b1       = (const float*)d_in[4];
    const float* W2       = (const float*)d_in[5];
    const float* b2       = (const float*)d_in[6];
    const float* Wd       = (const float*)d_in[7];
    const float* bd       = (const float*)d_in[8];
    float* out = (float*)d_out;

    char* base = (char*)d_ws;
    float*  G1v = (float*)base;                      base += (size_t)V_SZ * G4 * 4;
    float*  c1  = (float*)base;                      base += (size_t)B_SZ * H_SZ * 4;
    float*  c2  = (float*)base;                      base += (size_t)B_SZ * H_SZ * 4;
    ushort* h1b[2]; ushort* h2b[2];
    h1b[0] = (ushort*)base;                          base += (size_t)B_SZ * H_SZ * 2;
    h1b[1] = (ushort*)base;                          base += (size_t)B_SZ * H_SZ * 2;
    h2b[0] = (ushort*)base;                          base += (size_t)B_SZ * H_SZ * 2;
    h2b[1] = (ushort*)base;                          base += (size_t)B_SZ * H_SZ * 2;
    ushort* W1t = (ushort*)base;                     base += (size_t)G4 * H_SZ * 2;
    ushort* W2t = (ushort*)base;                     base += (size_t)G4 * 2 * H_SZ * 2;
    ushort* WdT = (ushort*)base;                     base += (size_t)V_SZ * H_SZ * 2;

    (void)hipMemsetAsync(d_out, 0, sizeof(float), stream);
    g1_kernel<<<(V_SZ * G4 + 255) / 256, 256, 0, stream>>>(emb, W1, b1, G1v);
    wtrans<<<(G4 * 256) / 256, 256, 0, stream>>>(W1, E_SZ, 8, W1t);
    wtrans<<<(G4 * 512) / 256, 256, 0, stream>>>(W2, 0, 9, W2t);
    wdtrans<<<(V_SZ * H_SZ + 255) / 256, 256, 0, stream>>>(Wd, WdT);

    dim3 grid(B_SZ / 128, H_SZ / 32, 2), blk(256);
    for (int t = 0; t <= T_SZ; t++) {
        const int Kend1 = (t < T_SZ) ? (t ? 256 : 0) : -1;
        const int Kend2 = (t >= 1) ? ((t >= 2) ? 512 : 256) : -1;
        lstm_fused<<<grid, blk, 0, stream>>>(
            (t && t < T_SZ) ? h1b[(t - 1) & 1] : nullptr, Kend1,
            features + t, G1v, c1, h1b[t & 1],
            (t >= 1) ? h1b[(t - 1) & 1] : nullptr,
            (t >= 2) ? h2b[(t - 2) & 1] : nullptr, Kend2,
            b2, c2, (t >= 1) ? h2b[(t - 1) & 1] : nullptr,
            W1t, W2t);
    }
    dense_loss<<<B_SZ / 64, 256, 0, stream>>>(h2b[(T_SZ - 1) & 1], WdT, bd, labels, out);
}

// Round 5
// 1588.560 us; speedup vs baseline: 5.8052x; 1.1998x over previous
//
#include <hip/hip_runtime.h>
#include <math.h>

#define B_SZ 4096
#define T_SZ 80
#define V_SZ 80
#define E_SZ 8
#define H_SZ 256
#define G4   1024   // 4*H

typedef __attribute__((ext_vector_type(8))) short short8;
typedef __attribute__((ext_vector_type(4))) float f32x4;

__device__ __forceinline__ float sigm(float x) {
    return 1.f / (1.f + __expf(-x));
}
__device__ __forceinline__ float tanhfast(float x) {
    x = fminf(fmaxf(x, -15.f), 15.f);
    float t = __expf(-2.f * x);
    return (1.f - t) / (1.f + t);
}
__device__ __forceinline__ ushort f2bf(float f) {   // RNE f32->bf16
    unsigned u = __float_as_uint(f);
    u = (u + 0x7fffu + ((u >> 16) & 1u)) >> 16;
    return (ushort)u;
}

// G1[v][col] = b1[col] + sum_e emb[v][e] * W1[e][col]
__global__ __launch_bounds__(256) void g1_kernel(const float* __restrict__ emb,
                                                 const float* __restrict__ W1,
                                                 const float* __restrict__ b1,
                                                 float* __restrict__ G1) {
    int idx = blockIdx.x * 256 + threadIdx.x;
    if (idx >= V_SZ * G4) return;
    int v = idx >> 10, col = idx & 1023;
    float g = b1[col];
#pragma unroll
    for (int e = 0; e < E_SZ; e++)
        g += emb[v * E_SZ + e] * W1[e * G4 + col];
    G1[idx] = g;
}

// Wt[n][k] = bf16(src[(k0+k)*1024 + n])
__global__ __launch_bounds__(256) void wtrans(const float* __restrict__ src, int k0,
                                              int Kshift, ushort* __restrict__ out) {
    const int K = 1 << Kshift;
    int idx = blockIdx.x * 256 + threadIdx.x;
    int n = idx >> Kshift, k = idx & (K - 1);
    out[idx] = f2bf(src[(size_t)(k0 + k) * G4 + n]);
}

// WdT[v][h] = bf16(Wd[h*V + v])
__global__ __launch_bounds__(256) void wdtrans(const float* __restrict__ src,
                                               ushort* __restrict__ out) {
    int idx = blockIdx.x * 256 + threadIdx.x;
    if (idx >= V_SZ * H_SZ) return;
    int v = idx >> 8, h = idx & 255;
    out[idx] = f2bf(src[h * V_SZ + v]);
}

// Fused step: blockIdx.z==0 -> layer1(t); z==1 -> layer2(t-1).
// Block = 128 rows x (4 gates x 32 hcols); 4 waves, wave w owns rows w*32..w*32+31.
// Double-buffered LDS, single barrier per K-tile, loads prefetched 1 tile ahead.
__global__ __launch_bounds__(256) void lstm_fused(
    const ushort* __restrict__ A1h, int Kend1,
    const int*   __restrict__ feat,   // features + t
    const float* __restrict__ G1,
    float* __restrict__ c1, ushort* __restrict__ h1out,
    const ushort* __restrict__ A2x, const ushort* __restrict__ A2h, int Kend2,
    const float* __restrict__ b2,
    float* __restrict__ c2, ushort* __restrict__ h2out,
    const ushort* __restrict__ W1t, const ushort* __restrict__ W2t) {

    const int z = blockIdx.z;
    const int Kend = z ? Kend2 : Kend1;
    if (Kend < 0) return;
    const int K = z ? 512 : 256;
    const ushort* __restrict__ Wt = z ? W2t : W1t;

    __shared__ ushort As[2][128 * 40];
    __shared__ ushort Ws[2][128 * 40];

    const int tid = threadIdx.x;
    const int w = tid >> 6, l = tid & 63;
    const int l15 = l & 15, l4 = l >> 4;
    const int m0 = blockIdx.x * 128;
    const int h0 = blockIdx.y * 32;

    // staging geometry: thread stages chunks (row0,c40) and (row1,c40) of A and W
    const int row0 = tid >> 2, c40 = tid & 3;       // rows 0..63
    const int row1 = row0 + 64;                     // rows 64..127
    const int ncol0 = (row0 >> 5) * 256 + h0 + (row0 & 31);
    const int ncol1 = (row1 >> 5) * 256 + h0 + (row1 & 31);
    const size_t wbase0 = (size_t)ncol0 * K + c40 * 8;
    const size_t wbase1 = (size_t)ncol1 * K + c40 * 8;
    const int lA0 = row0 * 40 + c40 * 8, lA1 = row1 * 40 + c40 * 8;

    // fragment read offsets (ushort indices)
    const int aoff0 = (w * 32 + l15) * 40 + l4 * 8;
    const int aoff1 = aoff0 + 16 * 40;
    const int boff  = l15 * 40 + l4 * 8;

    f32x4 acc[2][8];
    const f32x4 zero4 = {0.f, 0.f, 0.f, 0.f};
#pragma unroll
    for (int fg = 0; fg < 2; fg++)
#pragma unroll
        for (int cf = 0; cf < 8; cf++) acc[fg][cf] = zero4;

    auto loadTile = [&](int kt, short8& a0, short8& a1, short8& w0, short8& w1) {
        const ushort* Asrc; int kl;
        if (!z)            { Asrc = A1h; kl = kt; }
        else if (kt < 256) { Asrc = A2x; kl = kt; }
        else               { Asrc = A2h; kl = kt - 256; }
        a0 = *(const short8*)(Asrc + (size_t)(m0 + row0) * H_SZ + kl + c40 * 8);
        a1 = *(const short8*)(Asrc + (size_t)(m0 + row1) * H_SZ + kl + c40 * 8);
        w0 = *(const short8*)(Wt + wbase0 + kt);
        w1 = *(const short8*)(Wt + wbase1 + kt);
    };

    short8 ga0, ga1, gw0, gw1;
    if (Kend > 0) {
        // prologue: stage tile 0, prefetch tile 1
        loadTile(0, ga0, ga1, gw0, gw1);
        *(short8*)(As[0] + lA0) = ga0;
        *(short8*)(As[0] + lA1) = ga1;
        *(short8*)(Ws[0] + lA0) = gw0;
        *(short8*)(Ws[0] + lA1) = gw1;
        if (Kend > 32) loadTile(32, ga0, ga1, gw0, gw1);
        __syncthreads();
    }

    int cur = 0;
    for (int kt = 0; kt < Kend; kt += 32) {
        short8 a0 = *(const short8*)(As[cur] + aoff0);
        short8 a1 = *(const short8*)(As[cur] + aoff1);
        short8 bq[8];
#pragma unroll
        for (int cf = 0; cf < 8; cf++)
            bq[cf] = *(const short8*)(Ws[cur] + boff + cf * 640);

        __builtin_amdgcn_s_setprio(1);
#pragma unroll
        for (int cf = 0; cf < 8; cf++) {
            acc[0][cf] = __builtin_amdgcn_mfma_f32_16x16x32_bf16(a0, bq[cf], acc[0][cf], 0, 0, 0);
            acc[1][cf] = __builtin_amdgcn_mfma_f32_16x16x32_bf16(a1, bq[cf], acc[1][cf], 0, 0, 0);
        }
        __builtin_amdgcn_s_setprio(0);

        if (kt + 32 < Kend) {
            // write prefetched tile kt+32 into the other buffer
            *(short8*)(As[cur ^ 1] + lA0) = ga0;
            *(short8*)(As[cur ^ 1] + lA1) = ga1;
            *(short8*)(Ws[cur ^ 1] + lA0) = gw0;
            *(short8*)(Ws[cur ^ 1] + lA1) = gw1;
            if (kt + 64 < Kend) loadTile(kt + 64, ga0, ga1, gw0, gw1);
        }
        __syncthreads();
        cur ^= 1;
    }

    // fused LSTM cell epilogue. D layout: row=(l>>4)*4+r, col=l&15.
    float* __restrict__ cbuf = z ? c2 : c1;
    ushort* __restrict__ hout = z ? h2out : h1out;
    const bool cz = z ? (Kend == 256) : (Kend == 0);

#pragma unroll
    for (int fg = 0; fg < 2; fg++) {
#pragma unroll
        for (int r = 0; r < 4; r++) {
            const int grow = m0 + w * 32 + fg * 16 + l4 * 4 + r;
            const float* gb = z ? b2 : (G1 + (size_t)feat[(size_t)grow * T_SZ] * G4);
#pragma unroll
            for (int h16 = 0; h16 < 2; h16++) {
                const int hcol = h0 + h16 * 16 + l15;
                float gi = acc[fg][0 + h16][r] + gb[hcol];
                float gj = acc[fg][2 + h16][r] + gb[256 + hcol];
                float gf = acc[fg][4 + h16][r] + gb[512 + hcol];
                float go = acc[fg][6 + h16][r] + gb[768 + hcol];
                const size_t ci = (size_t)grow * H_SZ + hcol;
                float cp = cz ? 0.f : cbuf[ci];
                float cn = cp * sigm(gf + 1.f) + sigm(gi) * tanhfast(gj);
                float hn = tanhfast(cn) * sigm(go);
                cbuf[ci] = cn;
                hout[ci] = f2bf(hn);
            }
        }
    }
}

// dense+loss via MFMA: wave computes 16 rows x 80 v-cols; shfl softmax.
__global__ __launch_bounds__(256) void dense_loss(const ushort* __restrict__ h2,
                                                  const ushort* __restrict__ WdT,
                                                  const float* __restrict__ bd,
                                                  const int* __restrict__ labels,
                                                  float* __restrict__ out) {
    const int tid = threadIdx.x;
    const int w = tid >> 6, l = tid & 63;
    const int l15 = l & 15, l4 = l >> 4;
    const int m0 = blockIdx.x * 64 + w * 16;

    f32x4 acc[5];
    const f32x4 zero4 = {0.f, 0.f, 0.f, 0.f};
#pragma unroll
    for (int cf = 0; cf < 5; cf++) acc[cf] = zero4;

    for (int kt = 0; kt < 256; kt += 32) {
        short8 a = *(const short8*)(h2 + (size_t)(m0 + l15) * H_SZ + l4 * 8 + kt);
#pragma unroll
        for (int cf = 0; cf < 5; cf++) {
            short8 b = *(const short8*)(WdT + (size_t)(cf * 16 + l15) * H_SZ + l4 * 8 + kt);
            acc[cf] = __builtin_amdgcn_mfma_f32_16x16x32_bf16(a, b, acc[cf], 0, 0, 0);
        }
    }
#pragma unroll
    for (int cf = 0; cf < 5; cf++) {
        float bv = bd[cf * 16 + l15];
#pragma unroll
        for (int r = 0; r < 4; r++) acc[cf][r] += bv;
    }

#pragma unroll
    for (int r = 0; r < 4; r++) {
        const int row = m0 + l4 * 4 + r;
        float mx = acc[0][r];
#pragma unroll
        for (int cf = 1; cf < 5; cf++) mx = fmaxf(mx, acc[cf][r]);
#pragma unroll
        for (int msk = 1; msk < 16; msk <<= 1)
            mx = fmaxf(mx, __shfl_xor(mx, msk, 64));
        float s = 0.f;
#pragma unroll
        for (int cf = 0; cf < 5; cf++) s += __expf(acc[cf][r] - mx);
#pragma unroll
        for (int msk = 1; msk < 16; msk <<= 1)
            s += __shfl_xor(s, msk, 64);
        const int lab = labels[row];
        float pl = 0.f;
#pragma unroll
        for (int cf = 0; cf < 5; cf++)
            pl += (cf * 16 + l15 == lab) ? acc[cf][r] : 0.f;
#pragma unroll
        for (int msk = 1; msk < 16; msk <<= 1)
            pl += __shfl_xor(pl, msk, 64);
        if (l15 == 0)
            atomicAdd(out, (logf(s) + mx - pl) * (1.0f / B_SZ));
    }
}

extern "C" void kernel_launch(void* const* d_in, const int* in_sizes, int n_in,
                              void* d_out, int out_size, void* d_ws, size_t ws_size,
                              hipStream_t stream) {
    const int*   features = (const int*)d_in[0];
    const int*   labels   = (const int*)d_in[1];
    const float* emb      = (const float*)d_in[2];
    const float* W1       = (const float*)d_in[3];
    const float* b1       = (const float*)d_in[4];
    const float* W2       = (const float*)d_in[5];
    const float* b2       = (const float*)d_in[6];
    const float* Wd       = (const float*)d_in[7];
    const float* bd       = (const float*)d_in[8];
    float* out = (float*)d_out;

    char* base = (char*)d_ws;
    float*  G1v = (float*)base;                      base += (size_t)V_SZ * G4 * 4;
    float*  c1  = (float*)base;                      base += (size_t)B_SZ * H_SZ * 4;
    float*  c2  = (float*)base;                      base += (size_t)B_SZ * H_SZ * 4;
    ushort* h1b[2]; ushort* h2b[2];
    h1b[0] = (ushort*)base;                          base += (size_t)B_SZ * H_SZ * 2;
    h1b[1] = (ushort*)base;                          base += (size_t)B_SZ * H_SZ * 2;
    h2b[0] = (ushort*)base;                          base += (size_t)B_SZ * H_SZ * 2;
    h2b[1] = (ushort*)base;                          base += (size_t)B_SZ * H_SZ * 2;
    ushort* W1t = (ushort*)base;                     base += (size_t)G4 * H_SZ * 2;
    ushort* W2t = (ushort*)base;                     base += (size_t)G4 * 2 * H_SZ * 2;
    ushort* WdT = (ushort*)base;                     base += (size_t)V_SZ * H_SZ * 2;

    (void)hipMemsetAsync(d_out, 0, sizeof(float), stream);
    g1_kernel<<<(V_SZ * G4 + 255) / 256, 256, 0, stream>>>(emb, W1, b1, G1v);
    wtrans<<<(G4 * 256) / 256, 256, 0, stream>>>(W1, E_SZ, 8, W1t);
    wtrans<<<(G4 * 512) / 256, 256, 0, stream>>>(W2, 0, 9, W2t);
    wdtrans<<<(V_SZ * H_SZ + 255) / 256, 256, 0, stream>>>(Wd, WdT);

    dim3 grid(B_SZ / 128, H_SZ / 32, 2), blk(256);
    for (int t = 0; t <= T_SZ; t++) {
        const int Kend1 = (t < T_SZ) ? (t ? 256 : 0) : -1;
        const int Kend2 = (t >= 1) ? ((t >= 2) ? 512 : 256) : -1;
        lstm_fused<<<grid, blk, 0, stream>>>(
            (t && t < T_SZ) ? h1b[(t - 1) & 1] : nullptr, Kend1,
            features + t, G1v, c1, h1b[t & 1],
            (t >= 1) ? h1b[(t - 1) & 1] : nullptr,
            (t >= 2) ? h2b[(t - 2) & 1] : nullptr, Kend2,
            b2, c2, (t >= 1) ? h2b[(t - 1) & 1] : nullptr,
            W1t, W2t);
    }
    dense_loss<<<B_SZ / 64, 256, 0, stream>>>(h2b[(T_SZ - 1) & 1], WdT, bd, labels, out);
}